// Round 1
// baseline (518.027 us; speedup 1.0000x reference)
//
#include <hip/hip_runtime.h>
#include <math.h>

// Problem constants (from reference)
#define HN       250
#define WN       400
#define N_RAYS   (HN * WN)        // 100000
#define N_SAMP   1000000
#define P_TENSO  50000
#define C_CH     16
#define DIMV     8
#define STEP_SZ  0.005f
// DENSITY_SHIFT = 0.0 -> shift term 0; DENSITY_SCALE = min(1/(1-0),25) = 1.0
#define DENS_SCALE 1.0f

// One wave (64 lanes) per ray. Lanes = 4 sample-groups x 16 channels.
// ray_id is sorted -> each ray's samples are a contiguous run; bounds found
// by per-wave binary search (all lanes same address -> broadcast loads).
__global__ __launch_bounds__(256) void trivec_render_kernel(
    const float* __restrict__ trivecs,   // (P, 16, 3, 8)
    const float* __restrict__ densities, // (P, 16)
    const float* __restrict__ colors,    // (P, 16, 3)
    const float* __restrict__ gws,       // (N, 3)
    const float* __restrict__ gwl,       // (N, 3)
    const float* __restrict__ t_min,     // (N_RAYS)
    const float* __restrict__ bg,        // (3)
    const int*   __restrict__ gis,       // (N, 3)
    const int*   __restrict__ gil,       // (N, 3)
    const int*   __restrict__ tenso_id,  // (N)
    const int*   __restrict__ ray_id,    // (N), sorted
    const int*   __restrict__ step_id,   // (N)
    float* __restrict__ out)             // [5 * N_RAYS]: rgb(3,N), depth(N), alpha(N)
{
    const int lane = threadIdx.x & 63;
    const int r = blockIdx.x * 4 + (threadIdx.x >> 6);
    if (r >= N_RAYS) return;

    const int c = lane & 15;   // channel
    const int g = lane >> 4;   // sample subgroup 0..3

    // lower_bound(ray_id, r) and lower_bound(ray_id, r+1)
    int lo = 0, hi = N_SAMP;
    while (lo < hi) { int mid = (lo + hi) >> 1; if (ray_id[mid] < r) lo = mid + 1; else hi = mid; }
    const int seg_start = lo;
    hi = N_SAMP;
    while (lo < hi) { int mid = (lo + hi) >> 1; if (ray_id[mid] < r + 1) lo = mid + 1; else hi = mid; }
    const int seg_end = lo;

    const float tmin_r = t_min[r];

    float Tlog = 0.0f;                       // running cumulative log-transmittance
    float accR = 0.0f, accG = 0.0f, accB = 0.0f, accD = 0.0f;

    const int len = seg_end - seg_start;
    const int niter = (len + 3) >> 2;

    for (int it = 0; it < niter; ++it) {
        const int n = seg_start + it * 4 + g;
        const bool valid = (n < seg_end);
        const int nc = valid ? n : (seg_end - 1);   // clamp; masked later

        const int tid = tenso_id[nc];

        // trivec interpolation: feature[c] = prod_a (vs*ws + vl*wl)
        const float* tv = trivecs + (size_t)tid * (C_CH * 3 * DIMV) + c * (3 * DIMV);
        float f = 1.0f;
        #pragma unroll
        for (int a = 0; a < 3; ++a) {
            const int   is = gis[nc * 3 + a];
            const int   il = gil[nc * 3 + a];
            const float wS = gws[nc * 3 + a];
            const float wL = gwl[nc * 3 + a];
            const float vs = tv[a * DIMV + is];
            const float vl = tv[a * DIMV + il];
            f *= (vs * wS + vl * wL);
        }

        const float dns = densities[(size_t)tid * C_CH + c];
        const float* colp = colors + ((size_t)tid * C_CH + c) * 3;
        float s0 = f * dns;        // sigma partial
        float s1 = f * colp[0];    // color partials
        float s2 = f * colp[1];
        float s3 = f * colp[2];

        // reduce over 16 channels (xor masks 1,2,4,8 stay within the group)
        #pragma unroll
        for (int m = 1; m < 16; m <<= 1) {
            s0 += __shfl_xor(s0, m);
            s1 += __shfl_xor(s1, m);
            s2 += __shfl_xor(s2, m);
            s3 += __shfl_xor(s3, m);
        }

        // per-sample scalar math (replicated across the 16 lanes of the group)
        const float sigma = s0;
        // softplus(x) = max(x,0) + log1p(exp(-|x|))
        float dens = fmaxf(sigma, 0.0f) + __logf(1.0f + __expf(-fabsf(sigma)));
        dens *= DENS_SCALE;
        const float lt    = valid ? (-dens * STEP_SZ) : 0.0f;
        const float alpha = 1.0f - __expf(lt);          // 0 when invalid
        const float rr = 1.0f / (1.0f + __expf(-s1));
        const float gg = 1.0f / (1.0f + __expf(-s2));
        const float bb = 1.0f / (1.0f + __expf(-s3));
        const float z  = tmin_r + (float)step_id[nc] * STEP_SZ;

        // sequential (in-order) transmittance across the 4 groups
        const float lt0 = __shfl(lt, 0);
        const float lt1 = __shfl(lt, 16);
        const float lt2 = __shfl(lt, 32);
        const float lt3 = __shfl(lt, 48);
        float excl = Tlog;
        if (g > 0) excl += lt0;
        if (g > 1) excl += lt1;
        if (g > 2) excl += lt2;
        const float w = alpha * __expf(excl);
        Tlog += lt0 + lt1 + lt2 + lt3;

        accR += w * rr;
        accG += w * gg;
        accB += w * bb;
        accD += w * z;
    }

    // sum the 4 groups (values identical within each 16-lane group)
    accR += __shfl_xor(accR, 16); accR += __shfl_xor(accR, 32);
    accG += __shfl_xor(accG, 16); accG += __shfl_xor(accG, 32);
    accB += __shfl_xor(accB, 16); accB += __shfl_xor(accB, 32);
    accD += __shfl_xor(accD, 16); accD += __shfl_xor(accD, 32);

    const float bgw = __expf(Tlog);
    if (lane == 0) {
        out[0 * N_RAYS + r] = accR + bgw * bg[0];
        out[1 * N_RAYS + r] = accG + bgw * bg[1];
        out[2 * N_RAYS + r] = accB + bgw * bg[2];
        out[3 * N_RAYS + r] = accD;
        out[4 * N_RAYS + r] = 1.0f - bgw;
    }
}

extern "C" void kernel_launch(void* const* d_in, const int* in_sizes, int n_in,
                              void* d_out, int out_size, void* d_ws, size_t ws_size,
                              hipStream_t stream) {
    const float* trivecs   = (const float*)d_in[0];
    const float* densities = (const float*)d_in[1];
    const float* colors    = (const float*)d_in[2];
    const float* gws       = (const float*)d_in[3];
    const float* gwl       = (const float*)d_in[4];
    const float* t_min     = (const float*)d_in[5];
    const float* bg        = (const float*)d_in[6];
    const int*   gis       = (const int*)d_in[7];
    const int*   gil       = (const int*)d_in[8];
    const int*   tenso_id  = (const int*)d_in[9];
    const int*   ray_id    = (const int*)d_in[10];
    const int*   step_id   = (const int*)d_in[11];
    float* out = (float*)d_out;

    // 4 waves (rays) per 256-thread block
    const int blocks = (N_RAYS + 3) / 4;   // 25000
    trivec_render_kernel<<<blocks, 256, 0, stream>>>(
        trivecs, densities, colors, gws, gwl, t_min, bg,
        gis, gil, tenso_id, ray_id, step_id, out);
}

// Round 2
// 433.105 us; speedup vs baseline: 1.1961x; 1.1961x over previous
//
#include <hip/hip_runtime.h>
#include <math.h>

// Problem constants (from reference)
#define HN       250
#define WN       400
#define N_RAYS   (HN * WN)        // 100000
#define N_SAMP   1000000
#define P_TENSO  50000
#define C_CH     16
#define DIMV     8
#define STEP_SZ  0.005f
#define DENS_SCALE 1.0f           // min(1/(1-0), 25) = 1

// ---------------------------------------------------------------------------
// Layout transform pre-passes.
// trivecs (P,16,3,8) -> trivecs_t (P,3,8,16): a tap (a,idx) for all 16
// channels becomes ONE contiguous 64B line (was ~24 lines of slab touched
// per sample with ~25% byte utilization -> FETCH_SIZE 964 MB in R1).
// ---------------------------------------------------------------------------
__global__ __launch_bounds__(256) void transpose_trivecs(
    const float* __restrict__ in, float* __restrict__ out)
{
    // 2 tids per block: 768 floats, coalesced in and out via padded LDS.
    __shared__ float lds[2 * 400];          // 16 ch * 25 (pad +1/channel)
    const int tid0 = blockIdx.x * 2;
    const int t = threadIdx.x;
    #pragma unroll
    for (int i = 0; i < 3; ++i) {
        int l  = t + i * 256;               // 0..767 linear input order
        int tl = l / 384;
        int r  = l - tl * 384;              // c*24 + a*8 + d
        int c  = r / 24;
        int rem = r - c * 24;
        lds[tl * 400 + c * 25 + rem] = in[(size_t)tid0 * 384 + l];
    }
    __syncthreads();
    #pragma unroll
    for (int i = 0; i < 3; ++i) {
        int l  = t + i * 256;               // linear output order
        int tl = l / 384;
        int r  = l - tl * 384;              // a*128 + d*16 + c
        int a  = r >> 7;
        int d  = (r >> 4) & 7;
        int c  = r & 15;
        out[(size_t)tid0 * 384 + l] = lds[tl * 400 + c * 25 + a * 8 + d];
    }
}

// colors (P,16,3) -> colors_t (P,3,16): component-major so the 16 channel
// lanes load one 64B line per component. Reads scatter but colors is 9.6 MB
// (L2-resident); writes coalesced.
__global__ __launch_bounds__(256) void transpose_colors(
    const float* __restrict__ in, float* __restrict__ out)
{
    int j = blockIdx.x * 256 + threadIdx.x;
    if (j >= P_TENSO * 48) return;
    int tid = j / 48;
    int r   = j - tid * 48;
    int k   = r >> 4;
    int c   = r & 15;
    out[j] = in[(tid * 16 + c) * 3 + k];
}

// ---------------------------------------------------------------------------
// Main kernel: one wave per ray; lanes = 4 sample-groups x 16 channels.
// TRANSPOSED selects the ws-staged coalesced layout vs the raw input layout
// (fallback when ws_size is too small).
// ---------------------------------------------------------------------------
template <bool TRANSPOSED>
__global__ __launch_bounds__(256) void trivec_render_kernel(
    const float* __restrict__ trivecs,   // (P,16,3,8) or (P,3,8,16)
    const float* __restrict__ densities, // (P,16)
    const float* __restrict__ colors,    // (P,16,3) or (P,3,16)
    const float* __restrict__ gws,       // (N,3)
    const float* __restrict__ gwl,       // (N,3)
    const float* __restrict__ t_min,     // (N_RAYS)
    const float* __restrict__ bg,        // (3)
    const int*   __restrict__ gis,       // (N,3)
    const int*   __restrict__ gil,       // (N,3)
    const int*   __restrict__ tenso_id,  // (N)
    const int*   __restrict__ ray_id,    // (N), sorted
    const int*   __restrict__ step_id,   // (N)
    float* __restrict__ out)             // [5*N_RAYS]: rgb(3,N), depth, alpha
{
    const int lane = threadIdx.x & 63;
    const int r = blockIdx.x * 4 + (threadIdx.x >> 6);
    if (r >= N_RAYS) return;

    const int c = lane & 15;   // channel
    const int g = lane >> 4;   // sample subgroup 0..3

    // lower_bound(ray_id, r) / lower_bound(ray_id, r+1) — wave-uniform
    int lo = 0, hi = N_SAMP;
    while (lo < hi) { int mid = (lo + hi) >> 1; if (ray_id[mid] < r) lo = mid + 1; else hi = mid; }
    const int seg_start = lo;
    hi = N_SAMP;
    while (lo < hi) { int mid = (lo + hi) >> 1; if (ray_id[mid] < r + 1) lo = mid + 1; else hi = mid; }
    const int seg_end = lo;

    const float tmin_r = t_min[r];

    float Tlog = 0.0f;
    float accR = 0.0f, accG = 0.0f, accB = 0.0f, accD = 0.0f;

    const int len = seg_end - seg_start;
    const int niter = (len + 3) >> 2;

    for (int it = 0; it < niter; ++it) {
        const int n = seg_start + it * 4 + g;
        const bool valid = (n < seg_end);
        const int nc = valid ? n : (seg_end - 1);   // clamp; masked later

        const int tid = tenso_id[nc];

        float f = 1.0f;
        if (TRANSPOSED) {
            const float* tvb = trivecs + (size_t)tid * 384;  // (3,8,16)
            #pragma unroll
            for (int a = 0; a < 3; ++a) {
                const int   is = gis[nc * 3 + a];
                const int   il = gil[nc * 3 + a];
                const float wS = gws[nc * 3 + a];
                const float wL = gwl[nc * 3 + a];
                const float vs = tvb[a * 128 + is * 16 + c];  // 64B line / group
                const float vl = tvb[a * 128 + il * 16 + c];
                f *= (vs * wS + vl * wL);
            }
        } else {
            const float* tv = trivecs + (size_t)tid * 384 + c * 24;  // (16,3,8)
            #pragma unroll
            for (int a = 0; a < 3; ++a) {
                const int   is = gis[nc * 3 + a];
                const int   il = gil[nc * 3 + a];
                const float wS = gws[nc * 3 + a];
                const float wL = gwl[nc * 3 + a];
                const float vs = tv[a * 8 + is];
                const float vl = tv[a * 8 + il];
                f *= (vs * wS + vl * wL);
            }
        }

        const float dns = densities[(size_t)tid * C_CH + c];
        float s0 = f * dns;
        float s1, s2, s3;
        if (TRANSPOSED) {
            const float* cb = colors + (size_t)tid * 48;     // (3,16)
            s1 = f * cb[c];
            s2 = f * cb[16 + c];
            s3 = f * cb[32 + c];
        } else {
            const float* colp = colors + ((size_t)tid * C_CH + c) * 3;
            s1 = f * colp[0];
            s2 = f * colp[1];
            s3 = f * colp[2];
        }

        // reduce over 16 channels
        #pragma unroll
        for (int m = 1; m < 16; m <<= 1) {
            s0 += __shfl_xor(s0, m);
            s1 += __shfl_xor(s1, m);
            s2 += __shfl_xor(s2, m);
            s3 += __shfl_xor(s3, m);
        }

        const float sigma = s0;
        float dens = fmaxf(sigma, 0.0f) + __logf(1.0f + __expf(-fabsf(sigma)));
        dens *= DENS_SCALE;
        const float lt    = valid ? (-dens * STEP_SZ) : 0.0f;
        const float alpha = 1.0f - __expf(lt);
        const float rr = 1.0f / (1.0f + __expf(-s1));
        const float gg = 1.0f / (1.0f + __expf(-s2));
        const float bb = 1.0f / (1.0f + __expf(-s3));
        const float z  = tmin_r + (float)step_id[nc] * STEP_SZ;

        // in-order transmittance across the 4 groups
        const float lt0 = __shfl(lt, 0);
        const float lt1 = __shfl(lt, 16);
        const float lt2 = __shfl(lt, 32);
        const float lt3 = __shfl(lt, 48);
        float excl = Tlog;
        if (g > 0) excl += lt0;
        if (g > 1) excl += lt1;
        if (g > 2) excl += lt2;
        const float w = alpha * __expf(excl);
        Tlog += lt0 + lt1 + lt2 + lt3;

        accR += w * rr;
        accG += w * gg;
        accB += w * bb;
        accD += w * z;
    }

    accR += __shfl_xor(accR, 16); accR += __shfl_xor(accR, 32);
    accG += __shfl_xor(accG, 16); accG += __shfl_xor(accG, 32);
    accB += __shfl_xor(accB, 16); accB += __shfl_xor(accB, 32);
    accD += __shfl_xor(accD, 16); accD += __shfl_xor(accD, 32);

    const float bgw = __expf(Tlog);
    if (lane == 0) {
        out[0 * N_RAYS + r] = accR + bgw * bg[0];
        out[1 * N_RAYS + r] = accG + bgw * bg[1];
        out[2 * N_RAYS + r] = accB + bgw * bg[2];
        out[3 * N_RAYS + r] = accD;
        out[4 * N_RAYS + r] = 1.0f - bgw;
    }
}

extern "C" void kernel_launch(void* const* d_in, const int* in_sizes, int n_in,
                              void* d_out, int out_size, void* d_ws, size_t ws_size,
                              hipStream_t stream) {
    const float* trivecs   = (const float*)d_in[0];
    const float* densities = (const float*)d_in[1];
    const float* colors    = (const float*)d_in[2];
    const float* gws       = (const float*)d_in[3];
    const float* gwl       = (const float*)d_in[4];
    const float* t_min     = (const float*)d_in[5];
    const float* bg        = (const float*)d_in[6];
    const int*   gis       = (const int*)d_in[7];
    const int*   gil       = (const int*)d_in[8];
    const int*   tenso_id  = (const int*)d_in[9];
    const int*   ray_id    = (const int*)d_in[10];
    const int*   step_id   = (const int*)d_in[11];
    float* out = (float*)d_out;

    const size_t tv_elems  = (size_t)P_TENSO * 384;   // 19.2M floats
    const size_t col_elems = (size_t)P_TENSO * 48;    // 2.4M floats
    const size_t need = (tv_elems + col_elems) * sizeof(float);   // 86.4 MB

    const int blocks = (N_RAYS + 3) / 4;   // 25000, 4 waves/block

    if (ws_size >= need) {
        float* tv_t  = (float*)d_ws;
        float* col_t = tv_t + tv_elems;
        transpose_trivecs<<<P_TENSO / 2, 256, 0, stream>>>(trivecs, tv_t);
        transpose_colors<<<(P_TENSO * 48 + 255) / 256, 256, 0, stream>>>(colors, col_t);
        trivec_render_kernel<true><<<blocks, 256, 0, stream>>>(
            tv_t, densities, col_t, gws, gwl, t_min, bg,
            gis, gil, tenso_id, ray_id, step_id, out);
    } else {
        trivec_render_kernel<false><<<blocks, 256, 0, stream>>>(
            trivecs, densities, colors, gws, gwl, t_min, bg,
            gis, gil, tenso_id, ray_id, step_id, out);
    }
}